// Round 3
// baseline (104.628 us; speedup 1.0000x reference)
//
#include <hip/hip_runtime.h>

#define BQ   15      // queries
#define NIMG 40      // 15 queries + 25 supports
#define CH   64
#define HW   21
#define P    441     // 21*21
#define WIN  11
#define OH   11
#define OP   121     // 11*11
#define TP   231     // 11*21

// Gaussian window (sigma=1.5, 11 taps), compile-time constant.
__device__ __forceinline__ float Wf(int a) {
    constexpr float w[WIN] = {
        0.0010283804f, 0.0075988025f, 0.0360007770f, 0.1093606993f,
        0.2130055427f, 0.2660117290f, 0.2130055427f, 0.1093606993f,
        0.0360007770f, 0.0075988025f, 0.0010283804f};
    return w[a];
}

// ---------------------------------------------------------------------------
// k_ps: fused prep+stats. Grid 160 = 40 images x 4 channel-groups of 16.
// Phase A: wave reads 4 positions x 64ch (1024B contiguous per instruction),
//   16-lane shfl_xor tree -> per-position inv-norm, the 4 lanes owning this
//   block's channels write the normalized values TRANSPOSED into LDS
//   (stride 449 -> (c*449+p)%32 = (c+p+..)%32, conflict-free).
// Then: tn written per-channel in 441-float contiguous runs (fully coalesced),
//   and the separable blur of x / x^2 runs straight from the LDS tile --
//   stats' former global reload of tn is gone, as is one kernel boundary.
// LDS: tile 16*449 + t1/t2 8*232 each = 43.5 KB.
// ---------------------------------------------------------------------------
__global__ void __launch_bounds__(256) k_ps(const float* __restrict__ x1,
                                            const float* __restrict__ x2,
                                            float* __restrict__ tn,
                                            float* __restrict__ mu,
                                            float* __restrict__ sq,
                                            float* __restrict__ out) {
    __shared__ float tile[16 * 449];
    __shared__ float t1[8 * 232];
    __shared__ float t2[8 * 232];
    const int tid = threadIdx.x;
    if (blockIdx.x == 0 && tid < BQ * 5) out[tid] = 0.f;  // pairs runs later in-stream

    const int img = blockIdx.x >> 2, cg = blockIdx.x & 3;
    const float* src = (img < BQ) ? (x1 + (size_t)img * P * CH)
                                  : (x2 + (size_t)(img - BQ) * P * CH);
    const int wv = tid >> 6, grp = (tid & 63) >> 4, sub = tid & 15;

    // ---- Phase A: norm + transpose into LDS ----
#pragma unroll 4
    for (int it = 0; it < 28; ++it) {                 // 28*16 = 448 >= 441
        int p = it * 16 + wv * 4 + grp;
        float4 v = make_float4(0.f, 0.f, 0.f, 0.f);
        if (p < P) v = *reinterpret_cast<const float4*>(src + (size_t)p * CH + sub * 4);
        float s = fmaf(v.x, v.x, fmaf(v.y, v.y, fmaf(v.z, v.z, v.w * v.w)));
        s += __shfl_xor(s, 1, 64);                    // 16-lane group reduce
        s += __shfl_xor(s, 2, 64);
        s += __shfl_xor(s, 4, 64);
        s += __shfl_xor(s, 8, 64);
        int c0 = sub * 4 - cg * 16;                   // this block's tile channel
        if (p < P && c0 >= 0 && c0 < 16) {
            float inv = rsqrtf(s);
            tile[(c0 + 0) * 449 + p] = v.x * inv;
            tile[(c0 + 1) * 449 + p] = v.y * inv;
            tile[(c0 + 2) * 449 + p] = v.z * inv;
            tile[(c0 + 3) * 449 + p] = v.w * inv;
        }
    }
    __syncthreads();

    // ---- tn write: 16 channels x 441 contiguous floats ----
    {
        float* dst = tn + ((size_t)img * CH + cg * 16) * P;
        for (int i = tid; i < 16 * P; i += 256) {
            int c = i / P, p = i - c * P;
            dst[i] = tile[c * 449 + p];
        }
    }

    // ---- blur x and x^2, two passes of 8 channels ----
    for (int pass = 0; pass < 2; ++pass) {
        if (pass) __syncthreads();                    // protect t1/t2 reuse
        for (int i = tid; i < 8 * TP; i += 256) {
            int k = i / TP, t = i - k * TP;
            const float* x = tile + (pass * 8 + k) * 449;
            float a1 = 0.f, a2 = 0.f;
#pragma unroll
            for (int a = 0; a < WIN; ++a) {
                float v = x[t + 21 * a];
                a1 = fmaf(Wf(a), v, a1);
                a2 = fmaf(Wf(a) * v, v, a2);
            }
            t1[k * 232 + t] = a1;
            t2[k * 232 + t] = a2;
        }
        __syncthreads();
        for (int i = tid; i < 8 * OP; i += 256) {
            int k = i / OP, t = i - k * OP;
            int r = t / OH, cc = t - r * OH;
            int b0 = r * HW + cc;
            float a1 = 0.f, a2 = 0.f;
#pragma unroll
            for (int a = 0; a < WIN; ++a) {
                a1 = fmaf(Wf(a), t1[k * 232 + b0 + a], a1);
                a2 = fmaf(Wf(a), t2[k * 232 + b0 + a], a2);
            }
            size_t o = ((size_t)img * CH + cg * 16 + pass * 8 + k) * OP + t;
            mu[o] = a1;                               // coalesced: o == base + i
            sq[o] = a2;
        }
    }
}

// ---------------------------------------------------------------------------
// k_pairs: round-0 measured-best shape (grid 375 x 8, 8 channels/block)
// plus float4 X/Y loads and mu/sq register prefetch before the first barrier.
// LDS: xy 8*448, tb 8*232 = 21.8 KB -> 7 blocks/CU.
// ---------------------------------------------------------------------------
__global__ void __launch_bounds__(256) k_pairs(const float* __restrict__ tn,
                                               const float* __restrict__ mu,
                                               const float* __restrict__ sq,
                                               float* __restrict__ out) {
    __shared__ float xy[8 * 448];
    __shared__ float tb[8 * 232];
    __shared__ float ws4[4];
    const float C1 = 1e-4f, C2 = 9e-4f;
    const int tid = threadIdx.x;

    int pair = blockIdx.x;                 // 0..374
    int b = pair / 25, rem = pair - b * 25;
    int cb = blockIdx.y * 8;
    const float* X = tn + ((size_t)b * CH + cb) * P;
    const float* Y = tn + ((size_t)(BQ + rem) * CH + cb) * P;
    size_t oq = ((size_t)b * CH + cb) * OP;
    size_t os = ((size_t)(BQ + rem) * CH + cb) * OP;

    // register prefetch of mu/sq (coalesced; consumed after the blur barriers)
    float m1r[4], m2r[4], s1r[4], s2r[4];
#pragma unroll
    for (int j = 0; j < 4; ++j) {
        int i3 = tid + j * 256;
        int ii = (i3 < 8 * OP) ? i3 : 0;
        m1r[j] = mu[oq + ii]; m2r[j] = mu[os + ii];
        s1r[j] = sq[oq + ii]; s2r[j] = sq[os + ii];
    }

    const float4* X4 = reinterpret_cast<const float4*>(X);   // 8*441 % 4 == 0,
    const float4* Y4 = reinterpret_cast<const float4*>(Y);   // base 16B-aligned
    for (int i4 = tid; i4 < 8 * P / 4; i4 += 256) {          // 882 vec loads
        float4 xv = X4[i4], yv = Y4[i4];
        int e = i4 * 4;
#pragma unroll
        for (int j = 0; j < 4; ++j) {
            int ee = e + j;
            int k = ee / P, t = ee - k * P;
            xy[k * 448 + t] = (&xv.x)[j] * (&yv.x)[j];
        }
    }
    __syncthreads();
    for (int i = tid; i < 8 * TP; i += 256) {
        int k = i / TP, t = i - k * TP;
        const float* x = xy + k * 448;
        float a1 = 0.f;
#pragma unroll
        for (int a = 0; a < WIN; ++a) a1 = fmaf(Wf(a), x[t + 21 * a], a1);
        tb[k * 232 + t] = a1;
    }
    __syncthreads();

    float part = 0.f;
#pragma unroll
    for (int j = 0; j < 4; ++j) {
        int i3 = tid + j * 256;
        if (i3 < 8 * OP) {
            int k = i3 / OP, t = i3 - k * OP;
            int r = t / OH, cc = t - r * OH;
            float sxy = 0.f;
#pragma unroll
            for (int a = 0; a < WIN; ++a) sxy = fmaf(Wf(a), tb[k * 232 + r * HW + cc + a], sxy);
            float m1 = m1r[j], m2 = m2r[j];
            float v1 = s1r[j] - m1 * m1;
            float v2 = s2r[j] - m2 * m2;
            float cov = sxy - m1 * m2;
            part += ((2.f * m1 * m2 + C1) * (2.f * cov + C2)) /
                    ((m1 * m1 + m2 * m2 + C1) * (v1 + v2 + C2));
        }
    }
#pragma unroll
    for (int off = 32; off > 0; off >>= 1) part += __shfl_down(part, off, 64);
    if ((tid & 63) == 0) ws4[tid >> 6] = part;
    __syncthreads();
    if (tid == 0) {
        int n = rem / 5;
        atomicAdd(&out[b * 5 + n],
                  (ws4[0] + ws4[1] + ws4[2] + ws4[3]) * (1.0f / (CH * OP)));
    }
}

extern "C" void kernel_launch(void* const* d_in, const int* in_sizes, int n_in,
                              void* d_out, int out_size, void* d_ws, size_t ws_size,
                              hipStream_t stream) {
    const float* x1 = (const float*)d_in[0];   // (15, 441, 64)
    const float* x2 = (const float*)d_in[1];   // (5, 5, 441, 64)
    float* out = (float*)d_out;                // (15, 5)
    float* ws  = (float*)d_ws;

    float* tn = ws;                                  // 40*64*441
    float* mu = tn + (size_t)NIMG * CH * P;          // 2560*121
    float* sq = mu + (size_t)NIMG * CH * OP;         // 2560*121

    k_ps   <<<NIMG * 4, 256, 0, stream>>>(x1, x2, tn, mu, sq, out);
    k_pairs<<<dim3(375, 8), 256, 0, stream>>>(tn, mu, sq, out);
}

// Round 4
// 95.441 us; speedup vs baseline: 1.0963x; 1.0963x over previous
//
#include <hip/hip_runtime.h>

#define BQ   15      // queries
#define NIMG 40      // 15 queries + 25 supports, concatenated
#define CH   64
#define HW   21
#define P    441     // 21*21
#define WIN  11
#define OH   11
#define OP   121     // 11*11
#define TP   231     // 11*21

// Gaussian window (sigma=1.5, 11 taps), compile-time constant.
__device__ __forceinline__ float Wf(int a) {
    constexpr float w[WIN] = {
        0.0010283804f, 0.0075988025f, 0.0360007770f, 0.1093606993f,
        0.2130055427f, 0.2660117290f, 0.2130055427f, 0.1093606993f,
        0.0360007770f, 0.0075988025f, 0.0010283804f};
    return w[a];
}

// ---------------------------------------------------------------------------
// prep: normalize over channels + transpose (img, P, CH) -> tn (img, CH, P)
// grid (40, 7), block 256 — round-0 measured-best structure. Changes vs R0:
//  * float4 global loads (1008 vec loads; base p0*CH*4 is 16B-aligned)
//  * wave-parallel norm: 4 lanes/position (16ch each) + shfl_xor tree,
//    replacing the 64-deep serial chain on 63/256 threads. Bank pattern
//    65p+16q+c mod 32 -> exactly 2 lanes/bank (free).
// Store pattern unchanged (63-float = 252B contiguous runs).
// ---------------------------------------------------------------------------
__global__ void __launch_bounds__(256) prep_kernel(const float* __restrict__ x1,
                                                   const float* __restrict__ x2,
                                                   float* __restrict__ tn,
                                                   float* __restrict__ out) {
    if (blockIdx.x == 0 && blockIdx.y == 0 && threadIdx.x < BQ * 5)
        out[threadIdx.x] = 0.f;

    int img = blockIdx.x;           // 0..39
    int p0  = blockIdx.y * 63;      // 7 chunks of 63 = 441
    const float* src = (img < BQ) ? (x1 + (size_t)img * P * CH)
                                  : (x2 + (size_t)(img - BQ) * P * CH);
    float* dst = tn + (size_t)img * CH * P;

    __shared__ float tile[63 * 65];
    __shared__ float invn[63];

    const float4* src4 = reinterpret_cast<const float4*>(src + (size_t)p0 * CH);
    for (int i4 = threadIdx.x; i4 < 63 * CH / 4; i4 += 256) {   // 1008 vec loads
        float4 v = src4[i4];
        int e = i4 * 4, p = e >> 6, c = e & 63;
        float* d = &tile[p * 65 + c];
        d[0] = v.x; d[1] = v.y; d[2] = v.z; d[3] = v.w;
    }
    __syncthreads();
    if (threadIdx.x < 252) {                     // 63 pos * 4 lanes
        int p = threadIdx.x >> 2, q = threadIdx.x & 3;
        const float* row = tile + p * 65 + q * 16;
        float s = 0.f;
#pragma unroll
        for (int c = 0; c < 16; ++c) s = fmaf(row[c], row[c], s);
        s += __shfl_xor(s, 1, 64);               // 4-lane groups are wave-aligned
        s += __shfl_xor(s, 2, 64);
        if (q == 0) invn[p] = rsqrtf(s);
    }
    __syncthreads();
    for (int i = threadIdx.x; i < 63 * CH; i += 256) {
        int c = i / 63, p = i - c * 63;
        dst[(size_t)c * P + p0 + p] = tile[p * 65 + c] * invn[p];
    }
}

// ---------------------------------------------------------------------------
// stats: per channel-image, separable blur of x and x^2 -> mu, sq (121 each)
// grid 320, block 256; 8 channels per block — byte-identical to round 0.
// LDS layout per channel (stride 920): [0,441) data, [448,679) t1, [684,915) t2
// ---------------------------------------------------------------------------
__global__ void __launch_bounds__(256) stats_kernel(const float* __restrict__ tn,
                                                    float* __restrict__ mu,
                                                    float* __restrict__ sq) {
    __shared__ float lds[8 * 920];
    int cb = blockIdx.x * 8;        // global channel-image base, < 2560

    for (int i = threadIdx.x; i < 8 * P; i += 256) {
        int k = i / P, t = i - k * P;
        lds[k * 920 + t] = tn[(size_t)cb * P + i];
    }
    __syncthreads();
    for (int i = threadIdx.x; i < 8 * TP; i += 256) {
        int k = i / TP, t = i - k * TP;
        const float* x = lds + k * 920;
        float a1 = 0.f, a2 = 0.f;
#pragma unroll
        for (int a = 0; a < WIN; ++a) {
            float v = x[t + 21 * a];              // sequential addresses
            a1 = fmaf(Wf(a), v, a1);
            a2 = fmaf(Wf(a) * v, v, a2);
        }
        lds[k * 920 + 448 + t] = a1;
        lds[k * 920 + 684 + t] = a2;
    }
    __syncthreads();
    for (int i = threadIdx.x; i < 8 * OP; i += 256) {
        int k = i / OP, t = i - k * OP;
        int r = t / OH, cc = t - r * OH;
        int b0 = r * HW + cc;
        const float* t1 = lds + k * 920 + 448;
        const float* t2 = lds + k * 920 + 684;
        float a1 = 0.f, a2 = 0.f;
#pragma unroll
        for (int a = 0; a < WIN; ++a) {
            a1 = fmaf(Wf(a), t1[b0 + a], a1);
            a2 = fmaf(Wf(a), t2[b0 + a], a2);
        }
        size_t o = (size_t)(cb + k) * OP + t;
        mu[o] = a1;
        sq[o] = a2;
    }
}

// ---------------------------------------------------------------------------
// pairs: grid (375, 8), block 256; 8 channels per block, 3 barriers —
// round-0 measured-best structure. Changes vs R0:
//  * float4 X/Y loads (882 vec loads; base (b*CH+cb)*P % 4 == 0)
//  * mu/sq register prefetch hoisted above the first barrier (L2 latency
//    hides under the two blur phases).
// LDS: xy 8*448, t1 8*232 (within the same 21.9KB budget -> 7 blocks/CU).
// ---------------------------------------------------------------------------
__global__ void __launch_bounds__(256) pairs_kernel(const float* __restrict__ tn,
                                                    const float* __restrict__ mu,
                                                    const float* __restrict__ sq,
                                                    float* __restrict__ out) {
    __shared__ float xy[8 * 448];
    __shared__ float tb[8 * 232];
    __shared__ float ws4[4];
    const float C1 = 1e-4f, C2 = 9e-4f;
    const int tid = threadIdx.x;

    int pair = blockIdx.x;          // 0..374
    int b    = pair / 25;
    int rem  = pair - b * 25;       // support image index (n*5 + si)
    int cb   = blockIdx.y * 8;      // channel base

    const float* X = tn + ((size_t)b * CH + cb) * P;
    const float* Y = tn + ((size_t)(BQ + rem) * CH + cb) * P;
    size_t oq = ((size_t)b * CH + cb) * OP;
    size_t os = ((size_t)(BQ + rem) * CH + cb) * OP;

    // register prefetch of mu/sq (coalesced; consumed after the blur barriers)
    float m1r[4], m2r[4], s1r[4], s2r[4];
#pragma unroll
    for (int j = 0; j < 4; ++j) {
        int i3 = tid + j * 256;
        int ii = (i3 < 8 * OP) ? i3 : 0;
        m1r[j] = mu[oq + ii]; m2r[j] = mu[os + ii];
        s1r[j] = sq[oq + ii]; s2r[j] = sq[os + ii];
    }

    const float4* X4 = reinterpret_cast<const float4*>(X);
    const float4* Y4 = reinterpret_cast<const float4*>(Y);
    for (int i4 = tid; i4 < 8 * P / 4; i4 += 256) {          // 882 vec loads
        float4 xv = X4[i4], yv = Y4[i4];
        int e = i4 * 4;
#pragma unroll
        for (int j = 0; j < 4; ++j) {
            int ee = e + j;
            int k = ee / P, t = ee - k * P;
            xy[k * 448 + t] = (&xv.x)[j] * (&yv.x)[j];
        }
    }
    __syncthreads();
    for (int i = tid; i < 8 * TP; i += 256) {
        int k = i / TP, t = i - k * TP;
        const float* x = xy + k * 448;
        float a1 = 0.f;
#pragma unroll
        for (int a = 0; a < WIN; ++a) a1 = fmaf(Wf(a), x[t + 21 * a], a1);
        tb[k * 232 + t] = a1;
    }
    __syncthreads();

    float part = 0.f;
#pragma unroll
    for (int j = 0; j < 4; ++j) {
        int i3 = tid + j * 256;
        if (i3 < 8 * OP) {
            int k = i3 / OP, t = i3 - k * OP;
            int r = t / OH, cc = t - r * OH;
            float sxy = 0.f;
#pragma unroll
            for (int a = 0; a < WIN; ++a)
                sxy = fmaf(Wf(a), tb[k * 232 + r * HW + cc + a], sxy);
            float m1 = m1r[j], m2 = m2r[j];
            float v1 = s1r[j] - m1 * m1;
            float v2 = s2r[j] - m2 * m2;
            float cov = sxy - m1 * m2;
            part += ((2.f * m1 * m2 + C1) * (2.f * cov + C2)) /
                    ((m1 * m1 + m2 * m2 + C1) * (v1 + v2 + C2));
        }
    }

    // block reduce: 4 waves of 64
#pragma unroll
    for (int off = 32; off > 0; off >>= 1) part += __shfl_down(part, off, 64);
    if ((tid & 63) == 0) ws4[tid >> 6] = part;
    __syncthreads();
    if (tid == 0) {
        int n = rem / 5;
        atomicAdd(&out[b * 5 + n],
                  (ws4[0] + ws4[1] + ws4[2] + ws4[3]) * (1.0f / (CH * OP)));
    }
}

extern "C" void kernel_launch(void* const* d_in, const int* in_sizes, int n_in,
                              void* d_out, int out_size, void* d_ws, size_t ws_size,
                              hipStream_t stream) {
    const float* x1 = (const float*)d_in[0];   // (15, 441, 64)
    const float* x2 = (const float*)d_in[1];   // (5, 5, 441, 64)
    float* out = (float*)d_out;                // (15, 5)
    float* ws  = (float*)d_ws;

    float* tn = ws;                                  // 40*64*441
    float* mu = tn + (size_t)NIMG * CH * P;          // 2560*121
    float* sq = mu + (size_t)NIMG * CH * OP;         // 2560*121

    prep_kernel<<<dim3(NIMG, 7), 256, 0, stream>>>(x1, x2, tn, out);
    stats_kernel<<<NIMG * CH / 8, 256, 0, stream>>>(tn, mu, sq);
    pairs_kernel<<<dim3(375, 8), 256, 0, stream>>>(tn, mu, sq, out);
}